// Round 12
// baseline (827.686 us; speedup 1.0000x reference)
//
#include <hip/hip_runtime.h>
#include <stdint.h>

// ---------------------------------------------------------------------------
// JambaMambaMixer: B=1, L=2048, H=4096, D=8192, N=16, K=4, R=256
// R11: WAR-race hardening of gemm8p — lgkmcnt(0) BEFORE every window barrier
//      (reads provably complete before any post-barrier LDS overwrite) and an
//      extra {lgkmcnt(0); barrier} after the prologue pre-reads. The R4 body
//      relied on a ~100-300cy latency differential; absmax drift 0.0117 ->
//      0.027/0.031 across builds was its signature. Everything else = R10.
// ---------------------------------------------------------------------------

#define LSEQ 2048
#define HDIM 4096
#define DDIM 8192
#define NST  16
#define NPAD 384   // R + 2N = 288 padded to 3*128
#define NC   16    // scan chunks
#define CLEN 128   // LSEQ / NC

typedef __bf16 bf16x8 __attribute__((ext_vector_type(8)));
typedef float  f32x4  __attribute__((ext_vector_type(4)));

__device__ __forceinline__ ushort f2b(float f) {
  uint32_t x = __float_as_uint(f);
  x += 0x7FFFu + ((x >> 16) & 1u);           // RNE
  return (ushort)(x >> 16);
}
__device__ __forceinline__ float b2f(ushort u) {
  return __uint_as_float(((uint32_t)u) << 16);
}

__device__ __forceinline__ void gload_lds16(const ushort* g, ushort* l) {
  __builtin_amdgcn_global_load_lds(
      (const __attribute__((address_space(1))) void*)g,
      (__attribute__((address_space(3))) void*)l, 16, 0, 0);
}

// ---------------- f32 -> bf16 conversion (8 elems/thread) ------------------
__global__ __launch_bounds__(256) void cvt_kernel(const float* __restrict__ s,
                                                  ushort* __restrict__ d,
                                                  size_t n8) {
  size_t i = (size_t)blockIdx.x * 256 + threadIdx.x;
  if (i >= n8) return;
  const float4* sp = (const float4*)s;
  float4 a = sp[2 * i], b = sp[2 * i + 1];
  union { ushort us[8]; uint4 v; } u;
  u.us[0] = f2b(a.x); u.us[1] = f2b(a.y); u.us[2] = f2b(a.z); u.us[3] = f2b(a.w);
  u.us[4] = f2b(b.x); u.us[5] = f2b(b.y); u.us[6] = f2b(b.z); u.us[7] = f2b(b.w);
  ((uint4*)d)[i] = u.v;
}

// ======================= 256x256 bf16 NT GEMM (hardened R4 body) ============
// C[M,N] = A[M,K]*Bw[N,K]^T. 512 thr = 8 waves (2m x 4n), per-wave 128x64.
// Reads pipelined one window ahead; ONE barrier per window with lgkmcnt(0)
// drained BEFORE it (architectural WAR closure); vmcnt(6) at w3/w7 publishes
// the next LDS buffer (4x timing margin on the cross-wave RAW path).
// MODE 0: XCD chunk = 8m x (nbx/8)n per z-slice; z adds bOffZ/cOffZ.
// MODE 1: XCD chunk = 8m x 4n x 1z (grid (16,8,2)), z = K-slice.
// OUT 0: f32 store; OUT 1: bf16 store.
template <int MODE, int OUT>
__global__ __launch_bounds__(512, 2) void gemm8p(
    const ushort* __restrict__ A, const ushort* __restrict__ Bw,
    void* __restrict__ Cv, int M, int N, int ldk, int Kc,
    size_t bOffZ, size_t cOffZ) {
  __shared__ __align__(16) ushort As[2][256 * 64];
  __shared__ __align__(16) ushort Bs[2][256 * 64];
  const int tid  = threadIdx.x;
  const int lane = tid & 63;
  const int w    = tid >> 6;     // wave 0..7
  const int wr   = w >> 2;       // m half 0..1
  const int wc   = w & 3;        // n quarter 0..3

  int mt, nt, zz;
  size_t boff = 0, coff = 0;
  if (MODE == 0) {
    const int bid2 = blockIdx.y * gridDim.x + blockIdx.x;
    const int k8 = bid2 & 7, j = bid2 >> 3;
    mt = j & 7;                    // 8 m-tiles per XCD
    nt = k8 * (gridDim.x >> 3) + (j >> 3);
    zz = 0;
    boff = (size_t)blockIdx.z * bOffZ;
    coff = (size_t)blockIdx.z * cOffZ;
  } else {
    const int glob = (blockIdx.z * gridDim.y + blockIdx.y) * gridDim.x + blockIdx.x;
    const int k8 = glob & 7, j = glob >> 3;
    mt = j & 7;                    // 8 m-tiles per XCD
    nt = (k8 >> 1) * 4 + (j >> 3); // 4 n-tiles per XCD
    zz = k8 & 1;                   // single K-slice per XCD
  }
  const int m0 = mt * 256, n0 = nt * 256;
  const int kbeg = zz * Kc;
  const int NT = Kc >> 6;        // even, >= 4

  // staging constants: 16B slot pre-swizzle (involution)
  const int srck = (lane & 7) ^ ((lane >> 3) & 7);
  const int astripe = w >> 2, awl = w & 3;
  const int arow_st = astripe * 128 + awl * 8 + (lane >> 3);
  const ushort* Abase = A + (size_t)(m0 + arow_st) * ldk + kbeg + srck * 8;
  const int aldsb = (astripe * 128 + awl * 8) * 64;
  const int brow_st = w * 8 + (lane >> 3);
  const ushort* Bbase = Bw + boff + (size_t)(n0 + brow_st) * ldk + kbeg + srck * 8;
  const int bldsb = (w * 8) * 64;

  // read-side constants
  const int lrow = lane & 15;
  const int kch  = lane >> 4;
  const int axor = lrow & 7;

  auto stA = [&](int buf, int kt, int q) {
    gload_lds16(Abase + (size_t)q * 32 * ldk + kt * 64,
                &As[buf][aldsb + q * 32 * 64]);
  };
  auto stB = [&](int buf, int kt, int half, int jj) {
    gload_lds16(Bbase + (size_t)(half * 128 + jj * 64) * ldk + kt * 64,
                &Bs[buf][bldsb + (half * 128 + jj * 64) * 64]);
  };
  auto rdA = [&](int buf, int mi, int sl) -> bf16x8 {
    int arow = wr * 128 + mi * 16 + lrow;
    int s4 = sl * 4 + kch;
    return *(const bf16x8*)&As[buf][arow * 64 + ((s4 ^ axor) << 3)];
  };
  auto rdB = [&](int buf, int ni, int sl) -> bf16x8 {
    int brow = wc * 64 + ni * 16 + lrow;
    int s4 = sl * 4 + kch;
    return *(const bf16x8*)&Bs[buf][brow * 64 + ((s4 ^ axor) << 3)];
  };

  f32x4 acc[8][4] = {};
  bf16x8 afr[2][2][2];   // [parity][m2][sl]
  bf16x8 bfr[2][4][2];   // [parity][ni][sl]

#define RDAQ(BUF, Q, AP)                                                      \
  { _Pragma("unroll") for (int m2 = 0; m2 < 2; ++m2)                          \
      _Pragma("unroll") for (int sl = 0; sl < 2; ++sl)                        \
        afr[AP][m2][sl] = rdA(BUF, (Q) * 2 + m2, sl); }
#define RDBALL(BUF, BP)                                                       \
  { _Pragma("unroll") for (int ni = 0; ni < 4; ++ni)                          \
      _Pragma("unroll") for (int sl = 0; sl < 2; ++sl)                        \
        bfr[BP][ni][sl] = rdB(BUF, ni, sl); }
// lgkmcnt(0) BEFORE the barrier: all this wave's ds_reads complete before any
// wave can pass the barrier and issue an overwriting stage (WAR closure).
#define MFMA16(MQ, AP, BP)                                                    \
  { asm volatile("s_waitcnt lgkmcnt(0)" ::: "memory");                        \
    asm volatile("s_barrier" ::: "memory");                                   \
    __builtin_amdgcn_s_setprio(1);                                            \
    _Pragma("unroll") for (int sl = 0; sl < 2; ++sl)                          \
      _Pragma("unroll") for (int m2 = 0; m2 < 2; ++m2)                        \
        _Pragma("unroll") for (int ni = 0; ni < 4; ++ni)                      \
          acc[(MQ) * 2 + m2][ni] = __builtin_amdgcn_mfma_f32_16x16x32_bf16(   \
              afr[AP][m2][sl], bfr[BP][ni][sl], acc[(MQ) * 2 + m2][ni],       \
              0, 0, 0);                                                       \
    __builtin_amdgcn_s_setprio(0); }

  // prologue: stage t0 -> buf0 (8), t1 -> buf1 (8); wait buf0; pre-read w0 ops
  stB(0, 0, 0, 0); stB(0, 0, 0, 1); stB(0, 0, 1, 0); stB(0, 0, 1, 1);
  stA(0, 0, 0); stA(0, 0, 1); stA(0, 0, 2); stA(0, 0, 3);
  stB(1, 1, 0, 0); stB(1, 1, 0, 1); stB(1, 1, 1, 0); stB(1, 1, 1, 1);
  stA(1, 1, 0); stA(1, 1, 1); stA(1, 1, 2); stA(1, 1, 3);
  asm volatile("s_waitcnt vmcnt(8)" ::: "memory");   // buf0 landed (this wave)
  asm volatile("s_barrier" ::: "memory");            // all waves' buf0 landed
  RDBALL(0, 0);
  RDAQ(0, 0, 1);
  // close the prologue same-window race: pre-reads complete before the first
  // loop window can stage into buf0.
  asm volatile("s_waitcnt lgkmcnt(0)" ::: "memory");
  asm volatile("s_barrier" ::: "memory");

  for (int t = 0; t < NT; t += 2) {
    const int t2 = (t + 2 < NT) ? t + 2 : 0;   // wrap: valid mem, never MFMA'd
    const int t3 = (t + 3 < NT) ? t + 3 : 0;
    // w0: reads q1(buf0); stage B(t2)h0; MFMA Q0 buf0
    RDAQ(0, 1, 0);
    stB(0, t2, 0, 0); stB(0, t2, 0, 1);
    MFMA16(0, 1, 0);
    // w1
    RDAQ(0, 2, 1);
    stB(0, t2, 1, 0); stB(0, t2, 1, 1);
    MFMA16(1, 0, 0);
    // w2
    RDAQ(0, 3, 0);
    stA(0, t2, 0); stA(0, t2, 1);
    MFMA16(2, 1, 0);
    // w3: buf1 fully landed (vmcnt) -> pre-read its B + q0
    asm volatile("s_waitcnt vmcnt(6)" ::: "memory");
    RDBALL(1, 1);
    RDAQ(1, 0, 1);
    stA(0, t2, 2); stA(0, t2, 3);
    MFMA16(3, 0, 0);
    // w4
    RDAQ(1, 1, 0);
    stB(1, t3, 0, 0); stB(1, t3, 0, 1);
    MFMA16(0, 1, 1);
    // w5
    RDAQ(1, 2, 1);
    stB(1, t3, 1, 0); stB(1, t3, 1, 1);
    MFMA16(1, 0, 1);
    // w6
    RDAQ(1, 3, 0);
    stA(1, t3, 0); stA(1, t3, 1);
    MFMA16(2, 1, 1);
    // w7: buf0(t2) fully landed -> pre-read its B + q0
    asm volatile("s_waitcnt vmcnt(6)" ::: "memory");
    RDBALL(0, 0);
    RDAQ(0, 0, 1);
    stA(1, t3, 2); stA(1, t3, 3);
    MFMA16(3, 0, 1);
  }
#undef RDAQ
#undef RDBALL
#undef MFMA16

  asm volatile("s_waitcnt vmcnt(0)" ::: "memory");   // drain tail stages
  // epilogue: C/D layout col=lane&15, row=(lane>>4)*4+q
  float*  C  = (float*) Cv + (size_t)zz * M * N + coff;
  ushort* Cb = (ushort*)Cv + (size_t)zz * M * N + coff;
#pragma unroll
  for (int mi = 0; mi < 8; ++mi) {
    int row0 = m0 + wr * 128 + mi * 16 + kch * 4;
#pragma unroll
    for (int ni = 0; ni < 4; ++ni) {
      int col = n0 + wc * 64 + ni * 16 + lrow;
#pragma unroll
      for (int q_ = 0; q_ < 4; ++q_) {
        if (OUT == 0)
          C[(size_t)(row0 + q_) * N + col] = acc[mi][ni][q_];
        else
          Cb[(size_t)(row0 + q_) * N + col] = f2b(acc[mi][ni][q_]);
      }
    }
  }
}

// ---------------- 128x128 bf16 NT GEMM (narrow shapes) ----------------------
// EPI: 0 plain, 1 softplus(acc+bias). OBF: 0 f32 store, 1 bf16 store.
template <int EPI, int OBF>
__global__ __launch_bounds__(256) void gemm_nt(
    const ushort* __restrict__ A, const ushort* __restrict__ Bw,
    void* __restrict__ Cv, int M, int N, int ldk, int Kc,
    const float* __restrict__ bias) {
  __shared__ __align__(16) ushort As[128 * 64];
  __shared__ __align__(16) ushort Bs[128 * 64];
  const int tid  = threadIdx.x;
  const int lane = tid & 63;
  const int wid  = tid >> 6;
  const int wr = wid >> 1, wc = wid & 1;
  const int m0 = blockIdx.y * 128, n0 = blockIdx.x * 128;
  const int kbeg = blockIdx.z * Kc;
  float*  C  = (float*) Cv + (size_t)blockIdx.z * M * N;
  ushort* Cb = (ushort*)Cv + (size_t)blockIdx.z * M * N;
  const int rr0 = tid >> 3;
  const int sl  = tid & 7;
  const int lrow = lane & 15;
  const int lks  = lane >> 4;

  f32x4 acc[4][4] = {};

  for (int k0 = kbeg; k0 < kbeg + Kc; k0 += 64) {
#pragma unroll
    for (int i = 0; i < 4; ++i) {
      int rr  = i * 32 + rr0;
      int ksl = sl ^ (rr & 7);
      const ushort* ga = A  + (size_t)(m0 + rr) * ldk + k0 + ksl * 8;
      const ushort* gb = Bw + (size_t)(n0 + rr) * ldk + k0 + ksl * 8;
      ushort* la = As + (i * 256 + (wid << 6)) * 8;
      ushort* lb = Bs + (i * 256 + (wid << 6)) * 8;
      gload_lds16(ga, la);
      gload_lds16(gb, lb);
    }
    __syncthreads();
#pragma unroll
    for (int kc = 0; kc < 2; ++kc) {
      bf16x8 av[4], bv[4];
#pragma unroll
      for (int mi = 0; mi < 4; ++mi) {
        int row = wr * 64 + mi * 16 + lrow;
        int ks  = kc * 4 + lks;
        av[mi] = *(const bf16x8*)(As + row * 64 + ((ks ^ (row & 7)) << 3));
      }
#pragma unroll
      for (int ni = 0; ni < 4; ++ni) {
        int row = wc * 64 + ni * 16 + lrow;
        int ks  = kc * 4 + lks;
        bv[ni] = *(const bf16x8*)(Bs + row * 64 + ((ks ^ (row & 7)) << 3));
      }
#pragma unroll
      for (int mi = 0; mi < 4; ++mi)
#pragma unroll
        for (int ni = 0; ni < 4; ++ni)
          acc[mi][ni] = __builtin_amdgcn_mfma_f32_16x16x32_bf16(
              av[mi], bv[ni], acc[mi][ni], 0, 0, 0);
    }
    __syncthreads();
  }

#pragma unroll
  for (int mi = 0; mi < 4; ++mi) {
    int row0 = m0 + wr * 64 + mi * 16 + (lks << 2);
#pragma unroll
    for (int ni = 0; ni < 4; ++ni) {
      int col = n0 + wc * 64 + ni * 16 + lrow;
      float bcol = 0.f;
      if (EPI == 1) bcol = bias[col];
#pragma unroll
      for (int q = 0; q < 4; ++q) {
        float v = acc[mi][ni][q];
        if (EPI == 1) {
          v += bcol;
          v = (v > 20.f) ? v : log1pf(__expf(v));
        }
        if (OBF == 0) C [(size_t)(row0 + q) * N + col] = v;
        else          Cb[(size_t)(row0 + q) * N + col] = f2b(v);
      }
    }
  }
}

// ---------------- split-K reduce (out_proj) ---------------------------------
__global__ __launch_bounds__(256) void reduce2_kernel(
    const float* __restrict__ Cp, float* __restrict__ out) {
  size_t i = (size_t)blockIdx.x * 256 + threadIdx.x;
  const size_t MN4 = (size_t)LSEQ * HDIM / 4;
  float4 a = ((const float4*)Cp)[i];
  float4 b = ((const float4*)Cp)[MN4 + i];
  ((float4*)out)[i] = make_float4(a.x + b.x, a.y + b.y, a.z + b.z, a.w + b.w);
}

// ---------------- causal depthwise conv1d (K=4) + bias + SiLU --------------
// sliding window: block owns 256 d-channels x 16 l's; each u read once.
__global__ __launch_bounds__(256) void conv_silu_kernel(
    const ushort* __restrict__ ub, const float* __restrict__ cw,
    const float* __restrict__ cb, ushort* __restrict__ uc) {
  int d = blockIdx.x * 256 + threadIdx.x;
  int l0 = blockIdx.y * 16;
  float4 w4 = ((const float4*)cw)[d];
  float bsum = cb[d];
  float xm3 = (l0 >= 3) ? b2f(ub[(size_t)(l0 - 3) * DDIM + d]) : 0.f;
  float xm2 = (l0 >= 2) ? b2f(ub[(size_t)(l0 - 2) * DDIM + d]) : 0.f;
  float xm1 = (l0 >= 1) ? b2f(ub[(size_t)(l0 - 1) * DDIM + d]) : 0.f;
#pragma unroll
  for (int i = 0; i < 16; ++i) {
    int l = l0 + i;
    float xc = b2f(ub[(size_t)l * DDIM + d]);
    float s = bsum + w4.x * xm3 + w4.y * xm2 + w4.z * xm1 + w4.w * xc;
    float o = s / (1.f + __expf(-s));
    uc[(size_t)l * DDIM + d] = f2b(o);
    xm3 = xm2; xm2 = xm1; xm1 = xc;
  }
}

// ---------------- fused split-K reduce (x8) + RMSNorms -----------------------
__global__ __launch_bounds__(64) void norms_kernel(
    const float* __restrict__ Cp, const float* __restrict__ dtw,
    const float* __restrict__ bw, const float* __restrict__ cwn,
    ushort* __restrict__ dtn, float* __restrict__ Bn, float* __restrict__ Cn) {
  int l = blockIdx.x, lane = threadIdx.x;
  const size_t MN = (size_t)LSEQ * NPAD;
  const float* row = Cp + (size_t)l * NPAD;
  float va[4] = {0.f, 0.f, 0.f, 0.f};
#pragma unroll
  for (int z = 0; z < 8; ++z) {
    float4 v = ((const float4*)(row + z * MN))[lane];
    va[0] += v.x; va[1] += v.y; va[2] += v.z; va[3] += v.w;
  }
  float ss = va[0]*va[0] + va[1]*va[1] + va[2]*va[2] + va[3]*va[3];
#pragma unroll
  for (int m = 32; m >= 1; m >>= 1) ss += __shfl_xor(ss, m);
  float rs = rsqrtf(ss * (1.f / 256.f) + 1e-6f);
  float4 wv = ((const float4*)dtw)[lane];
  float wa[4] = {wv.x, wv.y, wv.z, wv.w};
  union { ushort us[4]; uint2 v2; } o;
#pragma unroll
  for (int jj = 0; jj < 4; ++jj) o.us[jj] = f2b(va[jj] * rs * wa[jj]);
  ((uint2*)(dtn + (size_t)l * 256))[lane] = o.v2;

  int g = lane & 15;
  float bv = 0.f, cv = 0.f;
#pragma unroll
  for (int z = 0; z < 8; ++z) {
    bv += row[z * MN + 256 + g];
    cv += row[z * MN + 272 + g];
  }
  float bs = bv * bv, cs = cv * cv;
#pragma unroll
  for (int m = 8; m >= 1; m >>= 1) {
    bs += __shfl_xor(bs, m);
    cs += __shfl_xor(cs, m);
  }
  if (lane < 16) {
    Bn[(size_t)l * NST + lane] = bv * rsqrtf(bs * (1.f / 16.f) + 1e-6f) * bw[lane];
    Cn[(size_t)l * NST + lane] = cv * rsqrtf(cs * (1.f / 16.f) + 1e-6f) * cwn[lane];
  }
}

// ---------------- selective scan, chunked over L (R8-verified) --------------
__global__ __launch_bounds__(256) void scan_phase1(
    const ushort* __restrict__ delta, const ushort* __restrict__ uc,
    const float* __restrict__ Bn, const float* __restrict__ Am,
    float* __restrict__ Sbuf, float* __restrict__ Pbuf) {
  __shared__ float sB[CLEN * NST];
  const int tid = threadIdx.x;
  const int d = blockIdx.x * 256 + tid;
  const int c = blockIdx.y, l0 = c * CLEN;
  {
    const float4* bsrc = (const float4*)(Bn + (size_t)l0 * NST);
    float4* bdst = (float4*)sB;
    for (int i = tid; i < CLEN * NST / 4; i += 256) bdst[i] = bsrc[i];
  }
  __syncthreads();
  float A[16];
#pragma unroll
  for (int jj = 0; jj < 4; ++jj) {
    float4 a4 = ((const float4*)(Am + (size_t)d * NST))[jj];
    A[4*jj] = a4.x; A[4*jj+1] = a4.y; A[4*jj+2] = a4.z; A[4*jj+3] = a4.w;
  }
  float st[16] = {};
  float sd = 0.f;
  const size_t base = (size_t)l0 * DDIM + d;
  float dx0 = b2f(delta[base]),  dx1 = b2f(delta[base + DDIM]);
  float ux0 = b2f(uc[base]),     ux1 = b2f(uc[base + DDIM]);
  for (int l = 0; l < CLEN; l += 2) {
    int lp = (l + 2 < CLEN) ? l + 2 : CLEN - 2;
    float dxn0 = b2f(delta[base + (size_t)lp * DDIM]);
    float dxn1 = b2f(delta[base + (size_t)(lp + 1) * DDIM]);
    float uxn0 = b2f(uc[base + (size_t)lp * DDIM]);
    float uxn1 = b2f(uc[base + (size_t)(lp + 1) * DDIM]);
    sd += dx0;
    float dxu = dx0 * ux0;
#pragma unroll
    for (int n = 0; n < 16; ++n)
      st[n] = fmaf(__expf(dx0 * A[n]), st[n], dxu * sB[l * NST + n]);
    sd += dx1;
    dxu = dx1 * ux1;
#pragma unroll
    for (int n = 0; n < 16; ++n)
      st[n] = fmaf(__expf(dx1 * A[n]), st[n], dxu * sB[(l + 1) * NST + n]);
    dx0 = dxn0; dx1 = dxn1; ux0 = uxn0; ux1 = uxn1;
  }
  float4* Sd = (float4*)(Sbuf + ((size_t)c * DDIM + d) * NST);
  float4* Pd = (float4*)(Pbuf + ((size_t)c * DDIM + d) * NST);
#pragma unroll
  for (int jj = 0; jj < 4; ++jj) {
    Sd[jj] = make_float4(st[4*jj], st[4*jj+1], st[4*jj+2], st[4*jj+3]);
    Pd[jj] = make_float4(__expf(A[4*jj] * sd),   __expf(A[4*jj+1] * sd),
                         __expf(A[4*jj+2] * sd), __expf(A[4*jj+3] * sd));
  }
}

__global__ __launch_bounds__(256) void scan_phase2(
    const float* __restrict__ Sbuf, float* __restrict__ Pbuf) {
  size_t t = (size_t)blockIdx.x * 256 + threadIdx.x;
  const size_t stride = (size_t)DDIM * NST;
  float s = 0.f;
  for (int c = 0; c < NC; ++c) {
    float P = Pbuf[c * stride + t];
    float S = Sbuf[c * stride + t];
    Pbuf[c * stride + t] = s;
    s = fmaf(P, s, S);
  }
}

__global__ __launch_bounds__(256) void scan_phase3(
    const ushort* __restrict__ delta, const ushort* __restrict__ uc,
    const float* __restrict__ Bn, const float* __restrict__ Cn,
    const float* __restrict__ Am, const float* __restrict__ Ibuf,
    const ushort* __restrict__ gb, const float* __restrict__ Dp,
    ushort* __restrict__ yg) {
  __shared__ float sB[CLEN * NST];
  __shared__ float sC[CLEN * NST];
  const int tid = threadIdx.x;
  const int d = blockIdx.x * 256 + tid;
  const int c = blockIdx.y, l0 = c * CLEN;
  {
    const float4* bsrc = (const float4*)(Bn + (size_t)l0 * NST);
    const float4* csrc = (const float4*)(Cn + (size_t)l0 * NST);
    float4* bdst = (float4*)sB;
    float4* cdst = (float4*)sC;
    for (int i = tid; i < CLEN * NST / 4; i += 256) {
      bdst[i] = bsrc[i];
      cdst[i] = csrc[i];
    }
  }
  __syncthreads();
  float A[16], st[16];
#pragma unroll
  for (int jj = 0; jj < 4; ++jj) {
    float4 a4 = ((const float4*)(Am + (size_t)d * NST))[jj];
    A[4*jj] = a4.x; A[4*jj+1] = a4.y; A[4*jj+2] = a4.z; A[4*jj+3] = a4.w;
    float4 s4 = ((const float4*)(Ibuf + ((size_t)c * DDIM + d) * NST))[jj];
    st[4*jj] = s4.x; st[4*jj+1] = s4.y; st[4*jj+2] = s4.z; st[4*jj+3] = s4.w;
  }
  const float Dpd = Dp[d];
  const size_t base = (size_t)l0 * DDIM + d;
  float dx0 = b2f(delta[base]),   dx1 = b2f(delta[base + DDIM]);
  float ux0 = b2f(uc[base]),      ux1 = b2f(uc[base + DDIM]);
  float g0  = b2f(gb[base]),      g1  = b2f(gb[base + DDIM]);
  for (int l = 0; l < CLEN; l += 2) {
    int lp = (l + 2 < CLEN) ? l + 2 : CLEN - 2;
    float dxn0 = b2f(delta[base + (size_t)lp * DDIM]);
    float dxn1 = b2f(delta[base + (size_t)(lp + 1) * DDIM]);
    float uxn0 = b2f(uc[base + (size_t)lp * DDIM]);
    float uxn1 = b2f(uc[base + (size_t)(lp + 1) * DDIM]);
    float gn0  = b2f(gb[base + (size_t)lp * DDIM]);
    float gn1  = b2f(gb[base + (size_t)(lp + 1) * DDIM]);
    {
      float dxu = dx0 * ux0, y0 = 0.f, y1 = 0.f;
#pragma unroll
      for (int n = 0; n < 16; n += 2) {
        st[n]   = fmaf(__expf(dx0 * A[n]),   st[n],   dxu * sB[l * NST + n]);
        st[n+1] = fmaf(__expf(dx0 * A[n+1]), st[n+1], dxu * sB[l * NST + n+1]);
        y0 = fmaf(st[n],   sC[l * NST + n],   y0);
        y1 = fmaf(st[n+1], sC[l * NST + n+1], y1);
      }
      float o = (y0 + y1 + ux0 * Dpd) * (g0 / (1.f + __expf(-g0)));
      yg[base + (size_t)l * DDIM] = f2b(o);
    }
    {
      float dxu = dx1 * ux1, y0 = 0.f, y1 = 0.f;
#pragma unroll
      for (int n = 0; n < 16; n += 2) {
        st[n]   = fmaf(__expf(dx1 * A[n]),   st[n],   dxu * sB[(l+1) * NST + n]);
        st[n+1] = fmaf(__expf(dx1 * A[n+1]), st[n+1], dxu * sB[(l+1) * NST + n+1]);
        y0 = fmaf(st[n],   sC[(l+1) * NST + n],   y0);
        y1 = fmaf(st[n+1], sC[(l+1) * NST + n+1], y1);
      }
      float o = (y0 + y1 + ux1 * Dpd) * (g1 / (1.f + __expf(-g1)));
      yg[base + (size_t)(l + 1) * DDIM] = f2b(o);
    }
    dx0 = dxn0; dx1 = dxn1; ux0 = uxn0; ux1 = uxn1; g0 = gn0; g1 = gn1;
  }
}

// ---------------------------------------------------------------------------
extern "C" void kernel_launch(void* const* d_in, const int* in_sizes, int n_in,
                              void* d_out, int out_size, void* d_ws, size_t ws_size,
                              hipStream_t stream) {
  (void)in_sizes; (void)n_in; (void)out_size; (void)ws_size;
  const float* hs   = (const float*)d_in[0];
  const float* W_in = (const float*)d_in[1];
  const float* cw   = (const float*)d_in[2];
  const float* cb   = (const float*)d_in[3];
  const float* Wx   = (const float*)d_in[4];
  const float* dtw  = (const float*)d_in[5];
  const float* bw   = (const float*)d_in[6];
  const float* cwn  = (const float*)d_in[7];
  const float* Wdt  = (const float*)d_in[8];
  const float* dtb  = (const float*)d_in[9];
  const float* Am   = (const float*)d_in[10];
  const float* Dp   = (const float*)d_in[11];
  const float* Wout = (const float*)d_in[12];
  float* out = (float*)d_out;

  char* ws = (char*)d_ws;
  const size_t MB = 1ull << 20;
  // region A (0-128MB): win_b for in_proj; after: delta_b (32MB) + wout_b (64MB)
  ushort* win_b   = (ushort*)(ws);
  ushort* delta_b = (ushort*)(ws);
  ushort* wout_b  = (ushort*)(ws + 64 * MB);
  // region B: ubuf bf16 (32MB @128); after conv: Cp(24 @128)+Sbuf(8 @152)+
  //           Pbuf(8 @160); out_proj partials Cp2 (64 @128)
  ushort* ubuf   = (ushort*)(ws + 128 * MB);
  float*  Cp     = (float*) (ws + 128 * MB);
  float*  Cp2    = (float*) (ws + 128 * MB);
  float*  Sbuf   = (float*) (ws + 152 * MB);
  float*  Pbuf   = (float*) (ws + 160 * MB);
  ushort* gbuf   = (ushort*)(ws + 192 * MB);          // 32MB (bf16 gate)
  ushort* hs_b   = (ushort*)(ws + 256 * MB);          // 16MB
  ushort* wxp_b  = (ushort*)(ws + 272 * MB);          // 6MB
  ushort* wdt_b  = (ushort*)(ws + 278 * MB);          // 4MB
  ushort* ucv    = (ushort*)(ws + 282 * MB);          // 32MB
  ushort* dtn    = (ushort*)(ws + 317 * MB);          // 1MB
  float*  Bn     = (float*) (ws + 318 * MB);
  float*  Cn     = (float*) (ws + 318 * MB + 131072);
  ushort* yg     = (ushort*)(ws + 319 * MB);          // 32MB; end 351MB

  // f32 -> bf16 conversions
  cvt_kernel<<<67108864 / 2048, 256, 0, stream>>>(W_in, win_b, 67108864 / 8);
  cvt_kernel<<<8388608 / 2048, 256, 0, stream>>>(hs, hs_b, 8388608 / 8);
  cvt_kernel<<<2359296 / 2048, 256, 0, stream>>>(Wx, wxp_b, 2359296 / 8);
  hipMemsetAsync((char*)wxp_b + 4718592, 0, 1572864, stream);
  cvt_kernel<<<2097152 / 2048, 256, 0, stream>>>(Wdt, wdt_b, 2097152 / 8);

  // 1) in_proj (hardened body, one z=2 dispatch): z=0 -> ubuf, z=1 -> gbuf
  gemm8p<0, 1><<<dim3(32, 8, 2), 512, 0, stream>>>(
      hs_b, win_b, ubuf, 2048, DDIM, 4096, 4096,
      (size_t)DDIM * 4096, (size_t)(gbuf - ubuf));
  cvt_kernel<<<33554432 / 2048, 256, 0, stream>>>(Wout, wout_b, 33554432 / 8);

  // 2) causal conv + SiLU -> u_conv bf16 (sliding window)
  conv_silu_kernel<<<dim3(32, 128), 256, 0, stream>>>(ubuf, cw, cb, ucv);

  // 3) x_proj, split-K x8 -> partials (reduce fused into norms)
  gemm_nt<0, 0><<<dim3(3, 16, 8), 256, 0, stream>>>(ucv, wxp_b, Cp,
                                                    2048, NPAD, 8192, 1024,
                                                    nullptr);
  // 4) fused reduce + RMSNorms
  norms_kernel<<<2048, 64, 0, stream>>>(Cp, dtw, bw, cwn, dtn, Bn, Cn);

  // 5) dt_proj + softplus -> delta bf16
  gemm_nt<1, 1><<<dim3(64, 16), 256, 0, stream>>>(dtn, wdt_b, delta_b,
                                                  2048, DDIM, 256, 256, dtb);

  // 6) chunked selective scan; phase3 fuses skip+gate -> yg bf16
  scan_phase1<<<dim3(32, NC), 256, 0, stream>>>(delta_b, ucv, Bn, Am, Sbuf, Pbuf);
  scan_phase2<<<512, 256, 0, stream>>>(Sbuf, Pbuf);
  scan_phase3<<<dim3(32, NC), 256, 0, stream>>>(delta_b, ucv, Bn, Cn, Am, Pbuf,
                                                gbuf, Dp, yg);

  // 7) out_proj (hardened body, 8m4n1z XCD chunks, split-K x2) -> reduce
  gemm8p<1, 0><<<dim3(16, 8, 2), 512, 0, stream>>>(yg, wout_b, Cp2,
                                                   2048, HDIM, 8192, 4096, 0, 0);
  reduce2_kernel<<<(LSEQ * HDIM / 4) / 256, 256, 0, stream>>>(Cp2, out);
}

// Round 13
// 800.831 us; speedup vs baseline: 1.0335x; 1.0335x over previous
//
#include <hip/hip_runtime.h>
#include <stdint.h>

// ---------------------------------------------------------------------------
// JambaMambaMixer: B=1, L=2048, H=4096, D=8192, N=16, K=4, R=256
// R12: single merged f32->bf16 conversion dispatch (cvt5: W_in, hs, Wx, Wdt,
//      Wout) with 16 elems/thread; wout_b moved to its own region (352MB) so
//      Wout's cvt no longer serializes after in_proj. GEMM bodies, scan,
//      norms, conv: byte-identical to R12's verified 0.0117-absmax build.
// ---------------------------------------------------------------------------

#define LSEQ 2048
#define HDIM 4096
#define DDIM 8192
#define NST  16
#define NPAD 384   // R + 2N = 288 padded to 3*128
#define NC   16    // scan chunks
#define CLEN 128   // LSEQ / NC

typedef __bf16 bf16x8 __attribute__((ext_vector_type(8)));
typedef float  f32x4  __attribute__((ext_vector_type(4)));

__device__ __forceinline__ ushort f2b(float f) {
  uint32_t x = __float_as_uint(f);
  x += 0x7FFFu + ((x >> 16) & 1u);           // RNE
  return (ushort)(x >> 16);
}
__device__ __forceinline__ float b2f(ushort u) {
  return __uint_as_float(((uint32_t)u) << 16);
}

__device__ __forceinline__ void gload_lds16(const ushort* g, ushort* l) {
  __builtin_amdgcn_global_load_lds(
      (const __attribute__((address_space(1))) void*)g,
      (__attribute__((address_space(3))) void*)l, 16, 0, 0);
}

// ---------------- merged f32 -> bf16 conversion (16 elems/thread) ----------
// One dispatch converts 5 tensors; block b selects its tensor via prefix
// boundaries o1..o4 (blocks per tensor = nelem/16/256, all sizes divisible).
__global__ __launch_bounds__(256) void cvt5_kernel(
    const float* __restrict__ s0, ushort* __restrict__ d0,
    const float* __restrict__ s1, ushort* __restrict__ d1,
    const float* __restrict__ s2, ushort* __restrict__ d2,
    const float* __restrict__ s3, ushort* __restrict__ d3,
    const float* __restrict__ s4, ushort* __restrict__ d4,
    int o1, int o2, int o3, int o4) {
  int b = blockIdx.x;
  const float* s; ushort* d; int lb;
  if (b < o1)      { s = s0; d = d0; lb = b; }
  else if (b < o2) { s = s1; d = d1; lb = b - o1; }
  else if (b < o3) { s = s2; d = d2; lb = b - o2; }
  else if (b < o4) { s = s3; d = d3; lb = b - o3; }
  else             { s = s4; d = d4; lb = b - o4; }
  size_t i = (size_t)lb * 256 + threadIdx.x;   // 16-element chunk index
  const float4* sp = (const float4*)s + i * 4;
  float4 a0 = sp[0], a1 = sp[1], a2 = sp[2], a3 = sp[3];
  union { ushort us[8]; uint4 v; } u0, u1;
  u0.us[0] = f2b(a0.x); u0.us[1] = f2b(a0.y); u0.us[2] = f2b(a0.z); u0.us[3] = f2b(a0.w);
  u0.us[4] = f2b(a1.x); u0.us[5] = f2b(a1.y); u0.us[6] = f2b(a1.z); u0.us[7] = f2b(a1.w);
  u1.us[0] = f2b(a2.x); u1.us[1] = f2b(a2.y); u1.us[2] = f2b(a2.z); u1.us[3] = f2b(a2.w);
  u1.us[4] = f2b(a3.x); u1.us[5] = f2b(a3.y); u1.us[6] = f2b(a3.z); u1.us[7] = f2b(a3.w);
  ((uint4*)d)[i * 2]     = u0.v;
  ((uint4*)d)[i * 2 + 1] = u1.v;
}

// ======================= 256x256 bf16 NT GEMM (hardened R4 body) ============
// C[M,N] = A[M,K]*Bw[N,K]^T. 512 thr = 8 waves (2m x 4n), per-wave 128x64.
// Reads pipelined one window ahead; ONE barrier per window with lgkmcnt(0)
// drained BEFORE it (architectural WAR closure); vmcnt(6) at w3/w7 publishes
// the next LDS buffer. VERIFIED R12: absmax 0.0117, deterministic. FROZEN.
// MODE 0: XCD chunk = 8m x (nbx/8)n per z-slice; z adds bOffZ/cOffZ.
// MODE 1: XCD chunk = 8m x 4n x 1z (grid (16,8,2)), z = K-slice.
// OUT 0: f32 store; OUT 1: bf16 store.
template <int MODE, int OUT>
__global__ __launch_bounds__(512, 2) void gemm8p(
    const ushort* __restrict__ A, const ushort* __restrict__ Bw,
    void* __restrict__ Cv, int M, int N, int ldk, int Kc,
    size_t bOffZ, size_t cOffZ) {
  __shared__ __align__(16) ushort As[2][256 * 64];
  __shared__ __align__(16) ushort Bs[2][256 * 64];
  const int tid  = threadIdx.x;
  const int lane = tid & 63;
  const int w    = tid >> 6;     // wave 0..7
  const int wr   = w >> 2;       // m half 0..1
  const int wc   = w & 3;        // n quarter 0..3

  int mt, nt, zz;
  size_t boff = 0, coff = 0;
  if (MODE == 0) {
    const int bid2 = blockIdx.y * gridDim.x + blockIdx.x;
    const int k8 = bid2 & 7, j = bid2 >> 3;
    mt = j & 7;                    // 8 m-tiles per XCD
    nt = k8 * (gridDim.x >> 3) + (j >> 3);
    zz = 0;
    boff = (size_t)blockIdx.z * bOffZ;
    coff = (size_t)blockIdx.z * cOffZ;
  } else {
    const int glob = (blockIdx.z * gridDim.y + blockIdx.y) * gridDim.x + blockIdx.x;
    const int k8 = glob & 7, j = glob >> 3;
    mt = j & 7;                    // 8 m-tiles per XCD
    nt = (k8 >> 1) * 4 + (j >> 3); // 4 n-tiles per XCD
    zz = k8 & 1;                   // single K-slice per XCD
  }
  const int m0 = mt * 256, n0 = nt * 256;
  const int kbeg = zz * Kc;
  const int NT = Kc >> 6;        // even, >= 4

  // staging constants: 16B slot pre-swizzle (involution)
  const int srck = (lane & 7) ^ ((lane >> 3) & 7);
  const int astripe = w >> 2, awl = w & 3;
  const int arow_st = astripe * 128 + awl * 8 + (lane >> 3);
  const ushort* Abase = A + (size_t)(m0 + arow_st) * ldk + kbeg + srck * 8;
  const int aldsb = (astripe * 128 + awl * 8) * 64;
  const int brow_st = w * 8 + (lane >> 3);
  const ushort* Bbase = Bw + boff + (size_t)(n0 + brow_st) * ldk + kbeg + srck * 8;
  const int bldsb = (w * 8) * 64;

  // read-side constants
  const int lrow = lane & 15;
  const int kch  = lane >> 4;
  const int axor = lrow & 7;

  auto stA = [&](int buf, int kt, int q) {
    gload_lds16(Abase + (size_t)q * 32 * ldk + kt * 64,
                &As[buf][aldsb + q * 32 * 64]);
  };
  auto stB = [&](int buf, int kt, int half, int jj) {
    gload_lds16(Bbase + (size_t)(half * 128 + jj * 64) * ldk + kt * 64,
                &Bs[buf][bldsb + (half * 128 + jj * 64) * 64]);
  };
  auto rdA = [&](int buf, int mi, int sl) -> bf16x8 {
    int arow = wr * 128 + mi * 16 + lrow;
    int s4 = sl * 4 + kch;
    return *(const bf16x8*)&As[buf][arow * 64 + ((s4 ^ axor) << 3)];
  };
  auto rdB = [&](int buf, int ni, int sl) -> bf16x8 {
    int brow = wc * 64 + ni * 16 + lrow;
    int s4 = sl * 4 + kch;
    return *(const bf16x8*)&Bs[buf][brow * 64 + ((s4 ^ axor) << 3)];
  };

  f32x4 acc[8][4] = {};
  bf16x8 afr[2][2][2];   // [parity][m2][sl]
  bf16x8 bfr[2][4][2];   // [parity][ni][sl]

#define RDAQ(BUF, Q, AP)                                                      \
  { _Pragma("unroll") for (int m2 = 0; m2 < 2; ++m2)                          \
      _Pragma("unroll") for (int sl = 0; sl < 2; ++sl)                        \
        afr[AP][m2][sl] = rdA(BUF, (Q) * 2 + m2, sl); }
#define RDBALL(BUF, BP)                                                       \
  { _Pragma("unroll") for (int ni = 0; ni < 4; ++ni)                          \
      _Pragma("unroll") for (int sl = 0; sl < 2; ++sl)                        \
        bfr[BP][ni][sl] = rdB(BUF, ni, sl); }
// lgkmcnt(0) BEFORE the barrier: all this wave's ds_reads complete before any
// wave can pass the barrier and issue an overwriting stage (WAR closure).
#define MFMA16(MQ, AP, BP)                                                    \
  { asm volatile("s_waitcnt lgkmcnt(0)" ::: "memory");                        \
    asm volatile("s_barrier" ::: "memory");                                   \
    __builtin_amdgcn_s_setprio(1);                                            \
    _Pragma("unroll") for (int sl = 0; sl < 2; ++sl)                          \
      _Pragma("unroll") for (int m2 = 0; m2 < 2; ++m2)                        \
        _Pragma("unroll") for (int ni = 0; ni < 4; ++ni)                      \
          acc[(MQ) * 2 + m2][ni] = __builtin_amdgcn_mfma_f32_16x16x32_bf16(   \
              afr[AP][m2][sl], bfr[BP][ni][sl], acc[(MQ) * 2 + m2][ni],       \
              0, 0, 0);                                                       \
    __builtin_amdgcn_s_setprio(0); }

  // prologue: stage t0 -> buf0 (8), t1 -> buf1 (8); wait buf0; pre-read w0 ops
  stB(0, 0, 0, 0); stB(0, 0, 0, 1); stB(0, 0, 1, 0); stB(0, 0, 1, 1);
  stA(0, 0, 0); stA(0, 0, 1); stA(0, 0, 2); stA(0, 0, 3);
  stB(1, 1, 0, 0); stB(1, 1, 0, 1); stB(1, 1, 1, 0); stB(1, 1, 1, 1);
  stA(1, 1, 0); stA(1, 1, 1); stA(1, 1, 2); stA(1, 1, 3);
  asm volatile("s_waitcnt vmcnt(8)" ::: "memory");   // buf0 landed (this wave)
  asm volatile("s_barrier" ::: "memory");            // all waves' buf0 landed
  RDBALL(0, 0);
  RDAQ(0, 0, 1);
  // close the prologue same-window race: pre-reads complete before the first
  // loop window can stage into buf0.
  asm volatile("s_waitcnt lgkmcnt(0)" ::: "memory");
  asm volatile("s_barrier" ::: "memory");

  for (int t = 0; t < NT; t += 2) {
    const int t2 = (t + 2 < NT) ? t + 2 : 0;   // wrap: valid mem, never MFMA'd
    const int t3 = (t + 3 < NT) ? t + 3 : 0;
    // w0: reads q1(buf0); stage B(t2)h0; MFMA Q0 buf0
    RDAQ(0, 1, 0);
    stB(0, t2, 0, 0); stB(0, t2, 0, 1);
    MFMA16(0, 1, 0);
    // w1
    RDAQ(0, 2, 1);
    stB(0, t2, 1, 0); stB(0, t2, 1, 1);
    MFMA16(1, 0, 0);
    // w2
    RDAQ(0, 3, 0);
    stA(0, t2, 0); stA(0, t2, 1);
    MFMA16(2, 1, 0);
    // w3: buf1 fully landed (vmcnt) -> pre-read its B + q0
    asm volatile("s_waitcnt vmcnt(6)" ::: "memory");
    RDBALL(1, 1);
    RDAQ(1, 0, 1);
    stA(0, t2, 2); stA(0, t2, 3);
    MFMA16(3, 0, 0);
    // w4
    RDAQ(1, 1, 0);
    stB(1, t3, 0, 0); stB(1, t3, 0, 1);
    MFMA16(0, 1, 1);
    // w5
    RDAQ(1, 2, 1);
    stB(1, t3, 1, 0); stB(1, t3, 1, 1);
    MFMA16(1, 0, 1);
    // w6
    RDAQ(1, 3, 0);
    stA(1, t3, 0); stA(1, t3, 1);
    MFMA16(2, 1, 1);
    // w7: buf0(t2) fully landed -> pre-read its B + q0
    asm volatile("s_waitcnt vmcnt(6)" ::: "memory");
    RDBALL(0, 0);
    RDAQ(0, 0, 1);
    stA(1, t3, 2); stA(1, t3, 3);
    MFMA16(3, 0, 1);
  }
#undef RDAQ
#undef RDBALL
#undef MFMA16

  asm volatile("s_waitcnt vmcnt(0)" ::: "memory");   // drain tail stages
  // epilogue: C/D layout col=lane&15, row=(lane>>4)*4+q
  float*  C  = (float*) Cv + (size_t)zz * M * N + coff;
  ushort* Cb = (ushort*)Cv + (size_t)zz * M * N + coff;
#pragma unroll
  for (int mi = 0; mi < 8; ++mi) {
    int row0 = m0 + wr * 128 + mi * 16 + kch * 4;
#pragma unroll
    for (int ni = 0; ni < 4; ++ni) {
      int col = n0 + wc * 64 + ni * 16 + lrow;
#pragma unroll
      for (int q_ = 0; q_ < 4; ++q_) {
        if (OUT == 0)
          C[(size_t)(row0 + q_) * N + col] = acc[mi][ni][q_];
        else
          Cb[(size_t)(row0 + q_) * N + col] = f2b(acc[mi][ni][q_]);
      }
    }
  }
}

// ---------------- 128x128 bf16 NT GEMM (narrow shapes) ----------------------
// EPI: 0 plain, 1 softplus(acc+bias). OBF: 0 f32 store, 1 bf16 store.
template <int EPI, int OBF>
__global__ __launch_bounds__(256) void gemm_nt(
    const ushort* __restrict__ A, const ushort* __restrict__ Bw,
    void* __restrict__ Cv, int M, int N, int ldk, int Kc,
    const float* __restrict__ bias) {
  __shared__ __align__(16) ushort As[128 * 64];
  __shared__ __align__(16) ushort Bs[128 * 64];
  const int tid  = threadIdx.x;
  const int lane = tid & 63;
  const int wid  = tid >> 6;
  const int wr = wid >> 1, wc = wid & 1;
  const int m0 = blockIdx.y * 128, n0 = blockIdx.x * 128;
  const int kbeg = blockIdx.z * Kc;
  float*  C  = (float*) Cv + (size_t)blockIdx.z * M * N;
  ushort* Cb = (ushort*)Cv + (size_t)blockIdx.z * M * N;
  const int rr0 = tid >> 3;
  const int sl  = tid & 7;
  const int lrow = lane & 15;
  const int lks  = lane >> 4;

  f32x4 acc[4][4] = {};

  for (int k0 = kbeg; k0 < kbeg + Kc; k0 += 64) {
#pragma unroll
    for (int i = 0; i < 4; ++i) {
      int rr  = i * 32 + rr0;
      int ksl = sl ^ (rr & 7);
      const ushort* ga = A  + (size_t)(m0 + rr) * ldk + k0 + ksl * 8;
      const ushort* gb = Bw + (size_t)(n0 + rr) * ldk + k0 + ksl * 8;
      ushort* la = As + (i * 256 + (wid << 6)) * 8;
      ushort* lb = Bs + (i * 256 + (wid << 6)) * 8;
      gload_lds16(ga, la);
      gload_lds16(gb, lb);
    }
    __syncthreads();
#pragma unroll
    for (int kc = 0; kc < 2; ++kc) {
      bf16x8 av[4], bv[4];
#pragma unroll
      for (int mi = 0; mi < 4; ++mi) {
        int row = wr * 64 + mi * 16 + lrow;
        int ks  = kc * 4 + lks;
        av[mi] = *(const bf16x8*)(As + row * 64 + ((ks ^ (row & 7)) << 3));
      }
#pragma unroll
      for (int ni = 0; ni < 4; ++ni) {
        int row = wc * 64 + ni * 16 + lrow;
        int ks  = kc * 4 + lks;
        bv[ni] = *(const bf16x8*)(Bs + row * 64 + ((ks ^ (row & 7)) << 3));
      }
#pragma unroll
      for (int mi = 0; mi < 4; ++mi)
#pragma unroll
        for (int ni = 0; ni < 4; ++ni)
          acc[mi][ni] = __builtin_amdgcn_mfma_f32_16x16x32_bf16(
              av[mi], bv[ni], acc[mi][ni], 0, 0, 0);
    }
    __syncthreads();
  }

#pragma unroll
  for (int mi = 0; mi < 4; ++mi) {
    int row0 = m0 + wr * 64 + mi * 16 + (lks << 2);
#pragma unroll
    for (int ni = 0; ni < 4; ++ni) {
      int col = n0 + wc * 64 + ni * 16 + lrow;
      float bcol = 0.f;
      if (EPI == 1) bcol = bias[col];
#pragma unroll
      for (int q = 0; q < 4; ++q) {
        float v = acc[mi][ni][q];
        if (EPI == 1) {
          v += bcol;
          v = (v > 20.f) ? v : log1pf(__expf(v));
        }
        if (OBF == 0) C [(size_t)(row0 + q) * N + col] = v;
        else          Cb[(size_t)(row0 + q) * N + col] = f2b(v);
      }
    }
  }
}

// ---------------- split-K reduce (out_proj) ---------------------------------
__global__ __launch_bounds__(256) void reduce2_kernel(
    const float* __restrict__ Cp, float* __restrict__ out) {
  size_t i = (size_t)blockIdx.x * 256 + threadIdx.x;
  const size_t MN4 = (size_t)LSEQ * HDIM / 4;
  float4 a = ((const float4*)Cp)[i];
  float4 b = ((const float4*)Cp)[MN4 + i];
  ((float4*)out)[i] = make_float4(a.x + b.x, a.y + b.y, a.z + b.z, a.w + b.w);
}

// ---------------- causal depthwise conv1d (K=4) + bias + SiLU --------------
// sliding window: block owns 256 d-channels x 16 l's; each u read once.
__global__ __launch_bounds__(256) void conv_silu_kernel(
    const ushort* __restrict__ ub, const float* __restrict__ cw,
    const float* __restrict__ cb, ushort* __restrict__ uc) {
  int d = blockIdx.x * 256 + threadIdx.x;
  int l0 = blockIdx.y * 16;
  float4 w4 = ((const float4*)cw)[d];
  float bsum = cb[d];
  float xm3 = (l0 >= 3) ? b2f(ub[(size_t)(l0 - 3) * DDIM + d]) : 0.f;
  float xm2 = (l0 >= 2) ? b2f(ub[(size_t)(l0 - 2) * DDIM + d]) : 0.f;
  float xm1 = (l0 >= 1) ? b2f(ub[(size_t)(l0 - 1) * DDIM + d]) : 0.f;
#pragma unroll
  for (int i = 0; i < 16; ++i) {
    int l = l0 + i;
    float xc = b2f(ub[(size_t)l * DDIM + d]);
    float s = bsum + w4.x * xm3 + w4.y * xm2 + w4.z * xm1 + w4.w * xc;
    float o = s / (1.f + __expf(-s));
    uc[(size_t)l * DDIM + d] = f2b(o);
    xm3 = xm2; xm2 = xm1; xm1 = xc;
  }
}

// ---------------- fused split-K reduce (x8) + RMSNorms -----------------------
__global__ __launch_bounds__(64) void norms_kernel(
    const float* __restrict__ Cp, const float* __restrict__ dtw,
    const float* __restrict__ bw, const float* __restrict__ cwn,
    ushort* __restrict__ dtn, float* __restrict__ Bn, float* __restrict__ Cn) {
  int l = blockIdx.x, lane = threadIdx.x;
  const size_t MN = (size_t)LSEQ * NPAD;
  const float* row = Cp + (size_t)l * NPAD;
  float va[4] = {0.f, 0.f, 0.f, 0.f};
#pragma unroll
  for (int z = 0; z < 8; ++z) {
    float4 v = ((const float4*)(row + z * MN))[lane];
    va[0] += v.x; va[1] += v.y; va[2] += v.z; va[3] += v.w;
  }
  float ss = va[0]*va[0] + va[1]*va[1] + va[2]*va[2] + va[3]*va[3];
#pragma unroll
  for (int m = 32; m >= 1; m >>= 1) ss += __shfl_xor(ss, m);
  float rs = rsqrtf(ss * (1.f / 256.f) + 1e-6f);
  float4 wv = ((const float4*)dtw)[lane];
  float wa[4] = {wv.x, wv.y, wv.z, wv.w};
  union { ushort us[4]; uint2 v2; } o;
#pragma unroll
  for (int jj = 0; jj < 4; ++jj) o.us[jj] = f2b(va[jj] * rs * wa[jj]);
  ((uint2*)(dtn + (size_t)l * 256))[lane] = o.v2;

  int g = lane & 15;
  float bv = 0.f, cv = 0.f;
#pragma unroll
  for (int z = 0; z < 8; ++z) {
    bv += row[z * MN + 256 + g];
    cv += row[z * MN + 272 + g];
  }
  float bs = bv * bv, cs = cv * cv;
#pragma unroll
  for (int m = 8; m >= 1; m >>= 1) {
    bs += __shfl_xor(bs, m);
    cs += __shfl_xor(cs, m);
  }
  if (lane < 16) {
    Bn[(size_t)l * NST + lane] = bv * rsqrtf(bs * (1.f / 16.f) + 1e-6f) * bw[lane];
    Cn[(size_t)l * NST + lane] = cv * rsqrtf(cs * (1.f / 16.f) + 1e-6f) * cwn[lane];
  }
}

// ---------------- selective scan, chunked over L (R8-verified) --------------
__global__ __launch_bounds__(256) void scan_phase1(
    const ushort* __restrict__ delta, const ushort* __restrict__ uc,
    const float* __restrict__ Bn, const float* __restrict__ Am,
    float* __restrict__ Sbuf, float* __restrict__ Pbuf) {
  __shared__ float sB[CLEN * NST];
  const int tid = threadIdx.x;
  const int d = blockIdx.x * 256 + tid;
  const int c = blockIdx.y, l0 = c * CLEN;
  {
    const float4* bsrc = (const float4*)(Bn + (size_t)l0 * NST);
    float4* bdst = (float4*)sB;
    for (int i = tid; i < CLEN * NST / 4; i += 256) bdst[i] = bsrc[i];
  }
  __syncthreads();
  float A[16];
#pragma unroll
  for (int jj = 0; jj < 4; ++jj) {
    float4 a4 = ((const float4*)(Am + (size_t)d * NST))[jj];
    A[4*jj] = a4.x; A[4*jj+1] = a4.y; A[4*jj+2] = a4.z; A[4*jj+3] = a4.w;
  }
  float st[16] = {};
  float sd = 0.f;
  const size_t base = (size_t)l0 * DDIM + d;
  float dx0 = b2f(delta[base]),  dx1 = b2f(delta[base + DDIM]);
  float ux0 = b2f(uc[base]),     ux1 = b2f(uc[base + DDIM]);
  for (int l = 0; l < CLEN; l += 2) {
    int lp = (l + 2 < CLEN) ? l + 2 : CLEN - 2;
    float dxn0 = b2f(delta[base + (size_t)lp * DDIM]);
    float dxn1 = b2f(delta[base + (size_t)(lp + 1) * DDIM]);
    float uxn0 = b2f(uc[base + (size_t)lp * DDIM]);
    float uxn1 = b2f(uc[base + (size_t)(lp + 1) * DDIM]);
    sd += dx0;
    float dxu = dx0 * ux0;
#pragma unroll
    for (int n = 0; n < 16; ++n)
      st[n] = fmaf(__expf(dx0 * A[n]), st[n], dxu * sB[l * NST + n]);
    sd += dx1;
    dxu = dx1 * ux1;
#pragma unroll
    for (int n = 0; n < 16; ++n)
      st[n] = fmaf(__expf(dx1 * A[n]), st[n], dxu * sB[(l + 1) * NST + n]);
    dx0 = dxn0; dx1 = dxn1; ux0 = uxn0; ux1 = uxn1;
  }
  float4* Sd = (float4*)(Sbuf + ((size_t)c * DDIM + d) * NST);
  float4* Pd = (float4*)(Pbuf + ((size_t)c * DDIM + d) * NST);
#pragma unroll
  for (int jj = 0; jj < 4; ++jj) {
    Sd[jj] = make_float4(st[4*jj], st[4*jj+1], st[4*jj+2], st[4*jj+3]);
    Pd[jj] = make_float4(__expf(A[4*jj] * sd),   __expf(A[4*jj+1] * sd),
                         __expf(A[4*jj+2] * sd), __expf(A[4*jj+3] * sd));
  }
}

__global__ __launch_bounds__(256) void scan_phase2(
    const float* __restrict__ Sbuf, float* __restrict__ Pbuf) {
  size_t t = (size_t)blockIdx.x * 256 + threadIdx.x;
  const size_t stride = (size_t)DDIM * NST;
  float s = 0.f;
  for (int c = 0; c < NC; ++c) {
    float P = Pbuf[c * stride + t];
    float S = Sbuf[c * stride + t];
    Pbuf[c * stride + t] = s;
    s = fmaf(P, s, S);
  }
}

__global__ __launch_bounds__(256) void scan_phase3(
    const ushort* __restrict__ delta, const ushort* __restrict__ uc,
    const float* __restrict__ Bn, const float* __restrict__ Cn,
    const float* __restrict__ Am, const float* __restrict__ Ibuf,
    const ushort* __restrict__ gb, const float* __restrict__ Dp,
    ushort* __restrict__ yg) {
  __shared__ float sB[CLEN * NST];
  __shared__ float sC[CLEN * NST];
  const int tid = threadIdx.x;
  const int d = blockIdx.x * 256 + tid;
  const int c = blockIdx.y, l0 = c * CLEN;
  {
    const float4* bsrc = (const float4*)(Bn + (size_t)l0 * NST);
    const float4* csrc = (const float4*)(Cn + (size_t)l0 * NST);
    float4* bdst = (float4*)sB;
    float4* cdst = (float4*)sC;
    for (int i = tid; i < CLEN * NST / 4; i += 256) {
      bdst[i] = bsrc[i];
      cdst[i] = csrc[i];
    }
  }
  __syncthreads();
  float A[16], st[16];
#pragma unroll
  for (int jj = 0; jj < 4; ++jj) {
    float4 a4 = ((const float4*)(Am + (size_t)d * NST))[jj];
    A[4*jj] = a4.x; A[4*jj+1] = a4.y; A[4*jj+2] = a4.z; A[4*jj+3] = a4.w;
    float4 s4 = ((const float4*)(Ibuf + ((size_t)c * DDIM + d) * NST))[jj];
    st[4*jj] = s4.x; st[4*jj+1] = s4.y; st[4*jj+2] = s4.z; st[4*jj+3] = s4.w;
  }
  const float Dpd = Dp[d];
  const size_t base = (size_t)l0 * DDIM + d;
  float dx0 = b2f(delta[base]),   dx1 = b2f(delta[base + DDIM]);
  float ux0 = b2f(uc[base]),      ux1 = b2f(uc[base + DDIM]);
  float g0  = b2f(gb[base]),      g1  = b2f(gb[base + DDIM]);
  for (int l = 0; l < CLEN; l += 2) {
    int lp = (l + 2 < CLEN) ? l + 2 : CLEN - 2;
    float dxn0 = b2f(delta[base + (size_t)lp * DDIM]);
    float dxn1 = b2f(delta[base + (size_t)(lp + 1) * DDIM]);
    float uxn0 = b2f(uc[base + (size_t)lp * DDIM]);
    float uxn1 = b2f(uc[base + (size_t)(lp + 1) * DDIM]);
    float gn0  = b2f(gb[base + (size_t)lp * DDIM]);
    float gn1  = b2f(gb[base + (size_t)(lp + 1) * DDIM]);
    {
      float dxu = dx0 * ux0, y0 = 0.f, y1 = 0.f;
#pragma unroll
      for (int n = 0; n < 16; n += 2) {
        st[n]   = fmaf(__expf(dx0 * A[n]),   st[n],   dxu * sB[l * NST + n]);
        st[n+1] = fmaf(__expf(dx0 * A[n+1]), st[n+1], dxu * sB[l * NST + n+1]);
        y0 = fmaf(st[n],   sC[l * NST + n],   y0);
        y1 = fmaf(st[n+1], sC[l * NST + n+1], y1);
      }
      float o = (y0 + y1 + ux0 * Dpd) * (g0 / (1.f + __expf(-g0)));
      yg[base + (size_t)l * DDIM] = f2b(o);
    }
    {
      float dxu = dx1 * ux1, y0 = 0.f, y1 = 0.f;
#pragma unroll
      for (int n = 0; n < 16; n += 2) {
        st[n]   = fmaf(__expf(dx1 * A[n]),   st[n],   dxu * sB[(l+1) * NST + n]);
        st[n+1] = fmaf(__expf(dx1 * A[n+1]), st[n+1], dxu * sB[(l+1) * NST + n+1]);
        y0 = fmaf(st[n],   sC[(l+1) * NST + n],   y0);
        y1 = fmaf(st[n+1], sC[(l+1) * NST + n+1], y1);
      }
      float o = (y0 + y1 + ux1 * Dpd) * (g1 / (1.f + __expf(-g1)));
      yg[base + (size_t)(l + 1) * DDIM] = f2b(o);
    }
    dx0 = dxn0; dx1 = dxn1; ux0 = uxn0; ux1 = uxn1; g0 = gn0; g1 = gn1;
  }
}

// ---------------------------------------------------------------------------
extern "C" void kernel_launch(void* const* d_in, const int* in_sizes, int n_in,
                              void* d_out, int out_size, void* d_ws, size_t ws_size,
                              hipStream_t stream) {
  (void)in_sizes; (void)n_in; (void)out_size; (void)ws_size;
  const float* hs   = (const float*)d_in[0];
  const float* W_in = (const float*)d_in[1];
  const float* cw   = (const float*)d_in[2];
  const float* cb   = (const float*)d_in[3];
  const float* Wx   = (const float*)d_in[4];
  const float* dtw  = (const float*)d_in[5];
  const float* bw   = (const float*)d_in[6];
  const float* cwn  = (const float*)d_in[7];
  const float* Wdt  = (const float*)d_in[8];
  const float* dtb  = (const float*)d_in[9];
  const float* Am   = (const float*)d_in[10];
  const float* Dp   = (const float*)d_in[11];
  const float* Wout = (const float*)d_in[12];
  float* out = (float*)d_out;

  char* ws = (char*)d_ws;
  const size_t MB = 1ull << 20;
  // region A (0-128MB): win_b for in_proj; after in_proj: delta_b (32MB)
  ushort* win_b   = (ushort*)(ws);
  ushort* delta_b = (ushort*)(ws);
  // region B: ubuf bf16 (32MB @128); after conv: Cp(24 @128)+Sbuf(8 @152)+
  //           Pbuf(8 @160); out_proj partials Cp2 (64 @128)
  ushort* ubuf   = (ushort*)(ws + 128 * MB);
  float*  Cp     = (float*) (ws + 128 * MB);
  float*  Cp2    = (float*) (ws + 128 * MB);
  float*  Sbuf   = (float*) (ws + 152 * MB);
  float*  Pbuf   = (float*) (ws + 160 * MB);
  ushort* gbuf   = (ushort*)(ws + 192 * MB);          // 32MB (bf16 gate)
  ushort* hs_b   = (ushort*)(ws + 256 * MB);          // 16MB
  ushort* wxp_b  = (ushort*)(ws + 272 * MB);          // 6MB
  ushort* wdt_b  = (ushort*)(ws + 278 * MB);          // 4MB
  ushort* ucv    = (ushort*)(ws + 282 * MB);          // 32MB
  ushort* dtn    = (ushort*)(ws + 317 * MB);          // 1MB
  float*  Bn     = (float*) (ws + 318 * MB);
  float*  Cn     = (float*) (ws + 318 * MB + 131072);
  ushort* yg     = (ushort*)(ws + 319 * MB);          // 32MB
  ushort* wout_b = (ushort*)(ws + 352 * MB);          // 64MB; end 416MB (<1GiB)

  // all five f32 -> bf16 conversions in ONE dispatch (wout_b no longer
  // overlaps win_b, so Wout's cvt can run before in_proj)
  // blocks: W_in 16384 | hs 2048 | Wx 576 | Wdt 512 | Wout 8192  -> 27712
  cvt5_kernel<<<27712, 256, 0, stream>>>(
      W_in, win_b, hs, hs_b, Wx, wxp_b, Wdt, wdt_b, Wout, wout_b,
      16384, 18432, 19008, 19520);
  hipMemsetAsync((char*)wxp_b + 4718592, 0, 1572864, stream);  // pad rows

  // 1) in_proj (hardened body, one z=2 dispatch): z=0 -> ubuf, z=1 -> gbuf
  gemm8p<0, 1><<<dim3(32, 8, 2), 512, 0, stream>>>(
      hs_b, win_b, ubuf, 2048, DDIM, 4096, 4096,
      (size_t)DDIM * 4096, (size_t)(gbuf - ubuf));

  // 2) causal conv + SiLU -> u_conv bf16 (sliding window)
  conv_silu_kernel<<<dim3(32, 128), 256, 0, stream>>>(ubuf, cw, cb, ucv);

  // 3) x_proj, split-K x8 -> partials (reduce fused into norms)
  gemm_nt<0, 0><<<dim3(3, 16, 8), 256, 0, stream>>>(ucv, wxp_b, Cp,
                                                    2048, NPAD, 8192, 1024,
                                                    nullptr);
  // 4) fused reduce + RMSNorms
  norms_kernel<<<2048, 64, 0, stream>>>(Cp, dtw, bw, cwn, dtn, Bn, Cn);

  // 5) dt_proj + softplus -> delta bf16
  gemm_nt<1, 1><<<dim3(64, 16), 256, 0, stream>>>(dtn, wdt_b, delta_b,
                                                  2048, DDIM, 256, 256, dtb);

  // 6) chunked selective scan; phase3 fuses skip+gate -> yg bf16
  scan_phase1<<<dim3(32, NC), 256, 0, stream>>>(delta_b, ucv, Bn, Am, Sbuf, Pbuf);
  scan_phase2<<<512, 256, 0, stream>>>(Sbuf, Pbuf);
  scan_phase3<<<dim3(32, NC), 256, 0, stream>>>(delta_b, ucv, Bn, Cn, Am, Pbuf,
                                                gbuf, Dp, yg);

  // 7) out_proj (hardened body, 8m4n1z XCD chunks, split-K x2) -> reduce
  gemm8p<1, 0><<<dim3(16, 8, 2), 512, 0, stream>>>(yg, wout_b, Cp2,
                                                   2048, HDIM, 8192, 4096, 0, 0);
  reduce2_kernel<<<(LSEQ * HDIM / 4) / 256, 256, 0, stream>>>(Cp2, out);
}